// Round 1
// baseline (514.695 us; speedup 1.0000x reference)
//
#include <hip/hip_runtime.h>
#include <cstdint>

// x: [4,4096,4096] fp32 -> rows of 128 over [T=16384, N_BANKS=32, BANK=128]
// scores = |x| + bias[bank][:]; mask = top-16 per row (ties -> lowest index);
// out0 = x * mask; out1 = num_assigned_tokens (pass-through).
#define BANKSZ   128
#define N_BANKS  32
#define TOPK     16
#define N_TOKENS (4 * 4096)
#define N_ROWS   (N_TOKENS * N_BANKS)           // 524288
#define N_PAIRS  (N_ROWS / 2)                   // 262144
#define OUT0_SZ  (N_TOKENS * N_BANKS * BANKSZ)  // 67108864
#define NAT_SZ   4096

#define NBLK           2048
#define WAVES_TOTAL    (NBLK * 4)                // 8192
#define PAIRS_PER_WAVE (N_PAIRS / WAVES_TOTAL)   // 32

typedef float f32x4 __attribute__((ext_vector_type(4)));

// float4 layout: one wave covers TWO rows per iteration.
//   lanes  0..31: row 2p, elements 4*l .. 4*l+3
//   lanes 32..63: row 2p+1, elements 4*(l-32) .. +3
// Every __ballot serves both rows at once: row A count = popc(low 32 bits),
// row B count = popc(high 32 bits). The two per-row threshold binary
// searches run interleaved in one instruction stream (2x ILP on the
// dependent probe chain). Global traffic is dwordx4 + nontemporal
// (read-once / write-once streaming; don't retain in L2).
//
// Threshold per row = 16th-largest monotone key: 5 parallel seed probes at
// the |N(0,1)| 16-of-128 order-statistic quantiles, branchless bracket,
// then a short dependent binary search with exact-count early collapse
// (exact for ANY data -- counts are monotone in the probe).
__global__ __launch_bounds__(256) void balanced_topk_kernel(
    const float* __restrict__ x,
    const float* __restrict__ bias,
    const float* __restrict__ nat,
    float* __restrict__ out)
{
    const int lane = threadIdx.x & 63;
    const int wid  = (blockIdx.x << 2) | (threadIdx.x >> 6);   // 0..8191

    // second output: pass-through, handled by the first 16 blocks
    if (blockIdx.x < (NAT_SZ / 256)) {
        const int i = blockIdx.x * 256 + threadIdx.x;
        out[(size_t)OUT0_SZ + i] = nat[i];
    }

    const int half = lane >> 5;    // 0: row 2p, 1: row 2p+1
    const int l32  = lane & 31;

    // banks of this wave's two rows: pair index strides by 8192 per iter,
    // so 2p mod 32 is invariant; row 2p bank is even, row 2p+1 is bank+1.
    const int bank = ((wid << 1) & (N_BANKS - 1)) + half;
    const f32x4 bv = ((const f32x4*)(bias + (size_t)bank * BANKSZ))[l32];

    const f32x4* __restrict__ x4 = (const f32x4*)x;
    f32x4*       __restrict__ o4 = (f32x4*)out;

    uint32_t idx = (uint32_t)wid * 64u + (uint32_t)lane;   // float4 index
    const uint32_t stride = (uint32_t)WAVES_TOTAL * 64u;   // 524288 f4/iter

    f32x4 v = __builtin_nontemporal_load(x4 + idx);

    for (int i = 0; i < PAIRS_PER_WAVE; ++i) {
        const f32x4  vc  = v;
        const uint32_t cur = idx;
        idx += stride;
        if (i != PAIRS_PER_WAVE - 1) v = __builtin_nontemporal_load(x4 + idx);

        const float s0 = fabsf(vc.x) + bv.x;
        const float s1 = fabsf(vc.y) + bv.y;
        const float s2 = fabsf(vc.z) + bv.z;
        const float s3 = fabsf(vc.w) + bv.w;

        // monotone float->uint key (exact for negative scores too)
        const uint32_t u0 = __float_as_uint(s0);
        const uint32_t u1 = __float_as_uint(s1);
        const uint32_t u2 = __float_as_uint(s2);
        const uint32_t u3 = __float_as_uint(s3);
        const uint32_t k0 = u0 ^ (uint32_t)(((int32_t)u0 >> 31) | 0x80000000);
        const uint32_t k1 = u1 ^ (uint32_t)(((int32_t)u1 >> 31) | 0x80000000);
        const uint32_t k2 = u2 ^ (uint32_t)(((int32_t)u2 >> 31) | 0x80000000);
        const uint32_t k3 = u3 ^ (uint32_t)(((int32_t)u3 >> 31) | 0x80000000);

        // one probe -> counts for BOTH rows (low/high 32 ballot bits)
#define CNT2(QV, CA, CB)                                                       \
        {                                                                      \
            const unsigned long long b0 = __ballot(k0 >= (QV));                \
            const unsigned long long b1 = __ballot(k1 >= (QV));                \
            const unsigned long long b2 = __ballot(k2 >= (QV));                \
            const unsigned long long b3 = __ballot(k3 >= (QV));                \
            CA = __popc((uint32_t)b0) + __popc((uint32_t)b1)                   \
               + __popc((uint32_t)b2) + __popc((uint32_t)b3);                  \
            CB = __popc((uint32_t)(b0 >> 32)) + __popc((uint32_t)(b1 >> 32))   \
               + __popc((uint32_t)(b2 >> 32)) + __popc((uint32_t)(b3 >> 32));  \
        }

        // 5 independent seed probes: keys of floats 1.25, 1.40625, 1.53125,
        // 1.65625, 1.8125 (key = bits | 0x80000000 for positive floats)
        int a1, b1c, a2, b2c, a3, b3c, a4, b4c, a5, b5c;
        CNT2(0xBFA00000u, a1, b1c);
        CNT2(0xBFB40000u, a2, b2c);
        CNT2(0xBFC40000u, a3, b3c);
        CNT2(0xBFD40000u, a4, b4c);
        CNT2(0xBFE80000u, a5, b5c);

        // branchless bracket per row: LO = largest seed with cnt>=16,
        // HI = smallest with cnt<16; exact-count collapse -> width-1 bracket
        uint32_t LA = 0u, HA = 0xFFFFFFFFu;
        if (a1 >= TOPK) LA = 0xBFA00000u;
        if (a2 >= TOPK) LA = 0xBFB40000u;
        if (a3 >= TOPK) LA = 0xBFC40000u;
        if (a4 >= TOPK) LA = 0xBFD40000u;
        if (a5 >= TOPK) LA = 0xBFE80000u;
        if (a5 <  TOPK) HA = 0xBFE80000u;
        if (a4 <  TOPK) HA = 0xBFD40000u;
        if (a3 <  TOPK) HA = 0xBFC40000u;
        if (a2 <  TOPK) HA = 0xBFB40000u;
        if (a1 <  TOPK) HA = 0xBFA00000u;
        if (a1 == TOPK) { LA = 0xBFA00000u; HA = 0xBFA00001u; }
        if (a2 == TOPK) { LA = 0xBFB40000u; HA = 0xBFB40001u; }
        if (a3 == TOPK) { LA = 0xBFC40000u; HA = 0xBFC40001u; }
        if (a4 == TOPK) { LA = 0xBFD40000u; HA = 0xBFD40001u; }
        if (a5 == TOPK) { LA = 0xBFE80000u; HA = 0xBFE80001u; }

        uint32_t LB = 0u, HB = 0xFFFFFFFFu;
        if (b1c >= TOPK) LB = 0xBFA00000u;
        if (b2c >= TOPK) LB = 0xBFB40000u;
        if (b3c >= TOPK) LB = 0xBFC40000u;
        if (b4c >= TOPK) LB = 0xBFD40000u;
        if (b5c >= TOPK) LB = 0xBFE80000u;
        if (b5c <  TOPK) HB = 0xBFE80000u;
        if (b4c <  TOPK) HB = 0xBFD40000u;
        if (b3c <  TOPK) HB = 0xBFC40000u;
        if (b2c <  TOPK) HB = 0xBFB40000u;
        if (b1c <  TOPK) HB = 0xBFA00000u;
        if (b1c == TOPK) { LB = 0xBFA00000u; HB = 0xBFA00001u; }
        if (b2c == TOPK) { LB = 0xBFB40000u; HB = 0xBFB40001u; }
        if (b3c == TOPK) { LB = 0xBFC40000u; HB = 0xBFC40001u; }
        if (b4c == TOPK) { LB = 0xBFD40000u; HB = 0xBFD40001u; }
        if (b5c == TOPK) { LB = 0xBFE80000u; HB = 0xBFE80001u; }

        // interleaved dependent tails: invariant cnt(LO) >= 16 > cnt(HI).
        // Both rows share each probe's 4 ballots; a collapsed row's updates
        // are masked off (branchless scalar cselects).
        while (((HA - LA) > 1u) || ((HB - LB) > 1u)) {
            const uint32_t QA = LA + ((HA - LA) >> 1);
            const uint32_t QB = LB + ((HB - LB) >> 1);
            const uint32_t Qv = half ? QB : QA;
            int cA, cB;
            CNT2(Qv, cA, cB);
            {
                const bool act = (HA - LA) > 1u;
                uint32_t nL = (cA >= TOPK) ? QA : LA;
                uint32_t nH = (cA >= TOPK) ? HA : QA;
                nH = (cA == TOPK) ? (QA + 1u) : nH;
                LA = act ? nL : LA;
                HA = act ? nH : HA;
            }
            {
                const bool act = (HB - LB) > 1u;
                uint32_t nL = (cB >= TOPK) ? QB : LB;
                uint32_t nH = (cB >= TOPK) ? HB : QB;
                nH = (cB == TOPK) ? (QB + 1u) : nH;
                LB = act ? nL : LB;
                HB = act ? nH : HB;
            }
        }
#undef CNT2

        // reconstruction: per-lane threshold of this lane's row
        const uint32_t T = half ? LB : LA;
        const unsigned long long g0 = __ballot(k0 >= T);
        const unsigned long long g1 = __ballot(k1 >= T);
        const unsigned long long g2 = __ballot(k2 >= T);
        const unsigned long long g3 = __ballot(k3 >= T);
        const int cgeA = __popc((uint32_t)g0) + __popc((uint32_t)g1)
                       + __popc((uint32_t)g2) + __popc((uint32_t)g3);
        const int cgeB = __popc((uint32_t)(g0 >> 32)) + __popc((uint32_t)(g1 >> 32))
                       + __popc((uint32_t)(g2 >> 32)) + __popc((uint32_t)(g3 >> 32));

        f32x4 o;
        if ((cgeA == TOPK) && (cgeB == TOPK)) {
            // no ties straddling either threshold (overwhelmingly common)
            o.x = (k0 >= T) ? vc.x : 0.0f;
            o.y = (k1 >= T) ? vc.y : 0.0f;
            o.z = (k2 >= T) ? vc.z : 0.0f;
            o.w = (k3 >= T) ? vc.w : 0.0f;
        } else {
            // ties at T: fill remaining r slots in element-index order
            const unsigned long long e0 = __ballot(k0 == T);
            const unsigned long long e1 = __ballot(k1 == T);
            const unsigned long long e2 = __ballot(k2 == T);
            const unsigned long long e3 = __ballot(k3 == T);
            const int tieA = __popc((uint32_t)e0) + __popc((uint32_t)e1)
                           + __popc((uint32_t)e2) + __popc((uint32_t)e3);
            const int tieB = __popc((uint32_t)(e0 >> 32)) + __popc((uint32_t)(e1 >> 32))
                           + __popc((uint32_t)(e2 >> 32)) + __popc((uint32_t)(e3 >> 32));
            const int cge = half ? cgeB : cgeA;
            const int tie = half ? tieB : tieA;
            const int r = TOPK - (cge - tie);
            const unsigned long long hm =
                half ? 0xFFFFFFFF00000000ull : 0x00000000FFFFFFFFull;
            const unsigned long long lt = ((1ull << lane) - 1ull) & hm;
            const int rank0 = __popcll(e0 & lt) + __popcll(e1 & lt)
                            + __popcll(e2 & lt) + __popcll(e3 & lt);
            const int rank1 = rank0 + ((k0 == T) ? 1 : 0);
            const int rank2 = rank1 + ((k1 == T) ? 1 : 0);
            const int rank3 = rank2 + ((k2 == T) ? 1 : 0);
            o.x = ((k0 > T) || ((k0 == T) && (rank0 < r))) ? vc.x : 0.0f;
            o.y = ((k1 > T) || ((k1 == T) && (rank1 < r))) ? vc.y : 0.0f;
            o.z = ((k2 > T) || ((k2 == T) && (rank2 < r))) ? vc.z : 0.0f;
            o.w = ((k3 > T) || ((k3 == T) && (rank3 < r))) ? vc.w : 0.0f;
        }
        __builtin_nontemporal_store(o, o4 + cur);
    }
}

extern "C" void kernel_launch(void* const* d_in, const int* in_sizes, int n_in,
                              void* d_out, int out_size, void* d_ws, size_t ws_size,
                              hipStream_t stream) {
    const float* x    = (const float*)d_in[0];
    const float* bias = (const float*)d_in[1];
    const float* nat  = (const float*)d_in[2];
    float* out = (float*)d_out;

    balanced_topk_kernel<<<dim3(NBLK), dim3(256), 0, stream>>>(x, bias, nat, out);
}

// Round 2
// 500.003 us; speedup vs baseline: 1.0294x; 1.0294x over previous
//
#include <hip/hip_runtime.h>
#include <cstdint>

// x: [4,4096,4096] fp32 -> rows of 128 over [T=16384, N_BANKS=32, BANK=128]
// scores = |x| + bias[bank][:]; mask = top-16 per row (ties -> lowest index);
// out0 = x * mask; out1 = num_assigned_tokens (pass-through).
#define BANKSZ   128
#define N_BANKS  32
#define TOPK     16
#define N_TOKENS (4 * 4096)
#define N_ROWS   (N_TOKENS * N_BANKS)           // 524288
#define N_PAIRS  (N_ROWS / 2)                   // 262144
#define OUT0_SZ  (N_TOKENS * N_BANKS * BANKSZ)  // 67108864
#define NAT_SZ   4096

#define NBLK           2048
#define WAVES_TOTAL    (NBLK * 4)                // 8192
#define PAIRS_PER_WAVE (N_PAIRS / WAVES_TOTAL)   // 32

typedef float f32x4 __attribute__((ext_vector_type(4)));

// float4 layout: one wave covers TWO rows per iteration.
//   lanes  0..31: row 2p, elements 4*l .. 4*l+3
//   lanes 32..63: row 2p+1, elements 4*(l-32) .. +3
// Every __ballot serves both rows at once: row A count = popc(low 32 bits),
// row B count = popc(high 32 bits). The two per-row threshold binary
// searches run interleaved in one instruction stream (2x ILP on the
// dependent probe chain).
// Plain cached loads/stores: x stays largely L3-resident across timed
// iterations (nt hints measured -85 us in round 1 -- latency-stalled at
// 2 TB/s / 17% VALUBusy). 2-deep prefetch keeps two loads in flight so a
// single slow load doesn't serialize the loop (vmcnt is in-order).
//
// Threshold per row = 16th-largest monotone key: 5 parallel seed probes at
// the |N(0,1)| 16-of-128 order-statistic quantiles, branchless bracket,
// then a short dependent binary search with exact-count early collapse
// (exact for ANY data -- counts are monotone in the probe).
__global__ __launch_bounds__(256) void balanced_topk_kernel(
    const float* __restrict__ x,
    const float* __restrict__ bias,
    const float* __restrict__ nat,
    float* __restrict__ out)
{
    const int lane = threadIdx.x & 63;
    const int wid  = (blockIdx.x << 2) | (threadIdx.x >> 6);   // 0..8191

    // second output: pass-through, handled by the first 16 blocks
    if (blockIdx.x < (NAT_SZ / 256)) {
        const int i = blockIdx.x * 256 + threadIdx.x;
        out[(size_t)OUT0_SZ + i] = nat[i];
    }

    const int half = lane >> 5;    // 0: row 2p, 1: row 2p+1
    const int l32  = lane & 31;

    // banks of this wave's two rows: pair index strides by 8192 per iter,
    // so 2p mod 32 is invariant; row 2p bank is even, row 2p+1 is bank+1.
    const int bank = ((wid << 1) & (N_BANKS - 1)) + half;
    const f32x4 bv = ((const f32x4*)(bias + (size_t)bank * BANKSZ))[l32];

    const f32x4* __restrict__ x4 = (const f32x4*)x;
    f32x4*       __restrict__ o4 = (f32x4*)out;

    uint32_t idx = (uint32_t)wid * 64u + (uint32_t)lane;   // float4 index
    const uint32_t stride = (uint32_t)WAVES_TOTAL * 64u;   // 524288 f4/iter

    // 2-deep software prefetch: two loads in flight at all times
    f32x4 v0 = x4[idx];
    f32x4 v1 = x4[idx + stride];

    for (int i = 0; i < PAIRS_PER_WAVE; ++i) {
        const f32x4  vc  = v0;
        const uint32_t cur = idx;
        v0 = v1;
        idx += stride;
        if (i + 2 < PAIRS_PER_WAVE) v1 = x4[idx + stride];

        const float s0 = fabsf(vc.x) + bv.x;
        const float s1 = fabsf(vc.y) + bv.y;
        const float s2 = fabsf(vc.z) + bv.z;
        const float s3 = fabsf(vc.w) + bv.w;

        // monotone float->uint key (exact for negative scores too)
        const uint32_t u0 = __float_as_uint(s0);
        const uint32_t u1 = __float_as_uint(s1);
        const uint32_t u2 = __float_as_uint(s2);
        const uint32_t u3 = __float_as_uint(s3);
        const uint32_t k0 = u0 ^ (uint32_t)(((int32_t)u0 >> 31) | 0x80000000);
        const uint32_t k1 = u1 ^ (uint32_t)(((int32_t)u1 >> 31) | 0x80000000);
        const uint32_t k2 = u2 ^ (uint32_t)(((int32_t)u2 >> 31) | 0x80000000);
        const uint32_t k3 = u3 ^ (uint32_t)(((int32_t)u3 >> 31) | 0x80000000);

        // one probe -> counts for BOTH rows (low/high 32 ballot bits)
#define CNT2(QV, CA, CB)                                                       \
        {                                                                      \
            const unsigned long long b0 = __ballot(k0 >= (QV));                \
            const unsigned long long b1 = __ballot(k1 >= (QV));                \
            const unsigned long long b2 = __ballot(k2 >= (QV));                \
            const unsigned long long b3 = __ballot(k3 >= (QV));                \
            CA = __popc((uint32_t)b0) + __popc((uint32_t)b1)                   \
               + __popc((uint32_t)b2) + __popc((uint32_t)b3);                  \
            CB = __popc((uint32_t)(b0 >> 32)) + __popc((uint32_t)(b1 >> 32))   \
               + __popc((uint32_t)(b2 >> 32)) + __popc((uint32_t)(b3 >> 32));  \
        }

        // 5 independent seed probes: keys of floats 1.25, 1.40625, 1.53125,
        // 1.65625, 1.8125 (key = bits | 0x80000000 for positive floats)
        int a1, b1c, a2, b2c, a3, b3c, a4, b4c, a5, b5c;
        CNT2(0xBFA00000u, a1, b1c);
        CNT2(0xBFB40000u, a2, b2c);
        CNT2(0xBFC40000u, a3, b3c);
        CNT2(0xBFD40000u, a4, b4c);
        CNT2(0xBFE80000u, a5, b5c);

        // branchless bracket per row: LO = largest seed with cnt>=16,
        // HI = smallest with cnt<16; exact-count collapse -> width-1 bracket
        uint32_t LA = 0u, HA = 0xFFFFFFFFu;
        if (a1 >= TOPK) LA = 0xBFA00000u;
        if (a2 >= TOPK) LA = 0xBFB40000u;
        if (a3 >= TOPK) LA = 0xBFC40000u;
        if (a4 >= TOPK) LA = 0xBFD40000u;
        if (a5 >= TOPK) LA = 0xBFE80000u;
        if (a5 <  TOPK) HA = 0xBFE80000u;
        if (a4 <  TOPK) HA = 0xBFD40000u;
        if (a3 <  TOPK) HA = 0xBFC40000u;
        if (a2 <  TOPK) HA = 0xBFB40000u;
        if (a1 <  TOPK) HA = 0xBFA00000u;
        if (a1 == TOPK) { LA = 0xBFA00000u; HA = 0xBFA00001u; }
        if (a2 == TOPK) { LA = 0xBFB40000u; HA = 0xBFB40001u; }
        if (a3 == TOPK) { LA = 0xBFC40000u; HA = 0xBFC40001u; }
        if (a4 == TOPK) { LA = 0xBFD40000u; HA = 0xBFD40001u; }
        if (a5 == TOPK) { LA = 0xBFE80000u; HA = 0xBFE80001u; }

        uint32_t LB = 0u, HB = 0xFFFFFFFFu;
        if (b1c >= TOPK) LB = 0xBFA00000u;
        if (b2c >= TOPK) LB = 0xBFB40000u;
        if (b3c >= TOPK) LB = 0xBFC40000u;
        if (b4c >= TOPK) LB = 0xBFD40000u;
        if (b5c >= TOPK) LB = 0xBFE80000u;
        if (b5c <  TOPK) HB = 0xBFE80000u;
        if (b4c <  TOPK) HB = 0xBFD40000u;
        if (b3c <  TOPK) HB = 0xBFC40000u;
        if (b2c <  TOPK) HB = 0xBFB40000u;
        if (b1c <  TOPK) HB = 0xBFA00000u;
        if (b1c == TOPK) { LB = 0xBFA00000u; HB = 0xBFA00001u; }
        if (b2c == TOPK) { LB = 0xBFB40000u; HB = 0xBFB40001u; }
        if (b3c == TOPK) { LB = 0xBFC40000u; HB = 0xBFC40001u; }
        if (b4c == TOPK) { LB = 0xBFD40000u; HB = 0xBFD40001u; }
        if (b5c == TOPK) { LB = 0xBFE80000u; HB = 0xBFE80001u; }

        // interleaved dependent tails: invariant cnt(LO) >= 16 > cnt(HI).
        // Both rows share each probe's 4 ballots; a collapsed row's updates
        // are masked off (branchless cselects).
        while (((HA - LA) > 1u) || ((HB - LB) > 1u)) {
            const uint32_t QA = LA + ((HA - LA) >> 1);
            const uint32_t QB = LB + ((HB - LB) >> 1);
            const uint32_t Qv = half ? QB : QA;
            int cA, cB;
            CNT2(Qv, cA, cB);
            {
                const bool act = (HA - LA) > 1u;
                uint32_t nL = (cA >= TOPK) ? QA : LA;
                uint32_t nH = (cA >= TOPK) ? HA : QA;
                nH = (cA == TOPK) ? (QA + 1u) : nH;
                LA = act ? nL : LA;
                HA = act ? nH : HA;
            }
            {
                const bool act = (HB - LB) > 1u;
                uint32_t nL = (cB >= TOPK) ? QB : LB;
                uint32_t nH = (cB >= TOPK) ? HB : QB;
                nH = (cB == TOPK) ? (QB + 1u) : nH;
                LB = act ? nL : LB;
                HB = act ? nH : HB;
            }
        }
#undef CNT2

        // reconstruction: per-lane threshold of this lane's row
        const uint32_t T = half ? LB : LA;
        const unsigned long long g0 = __ballot(k0 >= T);
        const unsigned long long g1 = __ballot(k1 >= T);
        const unsigned long long g2 = __ballot(k2 >= T);
        const unsigned long long g3 = __ballot(k3 >= T);
        const int cgeA = __popc((uint32_t)g0) + __popc((uint32_t)g1)
                       + __popc((uint32_t)g2) + __popc((uint32_t)g3);
        const int cgeB = __popc((uint32_t)(g0 >> 32)) + __popc((uint32_t)(g1 >> 32))
                       + __popc((uint32_t)(g2 >> 32)) + __popc((uint32_t)(g3 >> 32));

        f32x4 o;
        if ((cgeA == TOPK) && (cgeB == TOPK)) {
            // no ties straddling either threshold (overwhelmingly common)
            o.x = (k0 >= T) ? vc.x : 0.0f;
            o.y = (k1 >= T) ? vc.y : 0.0f;
            o.z = (k2 >= T) ? vc.z : 0.0f;
            o.w = (k3 >= T) ? vc.w : 0.0f;
        } else {
            // ties at T: fill remaining r slots in element-index order
            const unsigned long long e0 = __ballot(k0 == T);
            const unsigned long long e1 = __ballot(k1 == T);
            const unsigned long long e2 = __ballot(k2 == T);
            const unsigned long long e3 = __ballot(k3 == T);
            const int tieA = __popc((uint32_t)e0) + __popc((uint32_t)e1)
                           + __popc((uint32_t)e2) + __popc((uint32_t)e3);
            const int tieB = __popc((uint32_t)(e0 >> 32)) + __popc((uint32_t)(e1 >> 32))
                           + __popc((uint32_t)(e2 >> 32)) + __popc((uint32_t)(e3 >> 32));
            const int cge = half ? cgeB : cgeA;
            const int tie = half ? tieB : tieA;
            const int r = TOPK - (cge - tie);
            const unsigned long long hm =
                half ? 0xFFFFFFFF00000000ull : 0x00000000FFFFFFFFull;
            const unsigned long long lt = ((1ull << lane) - 1ull) & hm;
            const int rank0 = __popcll(e0 & lt) + __popcll(e1 & lt)
                            + __popcll(e2 & lt) + __popcll(e3 & lt);
            const int rank1 = rank0 + ((k0 == T) ? 1 : 0);
            const int rank2 = rank1 + ((k1 == T) ? 1 : 0);
            const int rank3 = rank2 + ((k2 == T) ? 1 : 0);
            o.x = ((k0 > T) || ((k0 == T) && (rank0 < r))) ? vc.x : 0.0f;
            o.y = ((k1 > T) || ((k1 == T) && (rank1 < r))) ? vc.y : 0.0f;
            o.z = ((k2 > T) || ((k2 == T) && (rank2 < r))) ? vc.z : 0.0f;
            o.w = ((k3 > T) || ((k3 == T) && (rank3 < r))) ? vc.w : 0.0f;
        }
        o4[cur] = o;
    }
}

extern "C" void kernel_launch(void* const* d_in, const int* in_sizes, int n_in,
                              void* d_out, int out_size, void* d_ws, size_t ws_size,
                              hipStream_t stream) {
    const float* x    = (const float*)d_in[0];
    const float* bias = (const float*)d_in[1];
    const float* nat  = (const float*)d_in[2];
    float* out = (float*)d_out;

    balanced_topk_kernel<<<dim3(NBLK), dim3(256), 0, stream>>>(x, bias, nat, out);
}

// Round 3
// 487.125 us; speedup vs baseline: 1.0566x; 1.0264x over previous
//
#include <hip/hip_runtime.h>
#include <cstdint>

// x: [4,4096,4096] fp32 -> rows of 128 over [T=16384, N_BANKS=32, BANK=128]
// scores = |x| + bias[bank][:]; mask = top-16 per row (ties -> lowest index);
// out0 = x * mask; out1 = num_assigned_tokens (pass-through).
//
// REVERTED to the round-0 float2 structure (measured ~110 us kernel / 443 us
// bench). The float4 2-row pair restructure measured 195-199 us in rounds 1-2
// (latency-stalled, 17% VALUBusy) regardless of nt hints or prefetch depth --
// do not reintroduce it.
#define BANKSZ   128
#define N_BANKS  32
#define TOPK     16
#define N_TOKENS (4 * 4096)
#define N_ROWS   (N_TOKENS * N_BANKS)           // 524288
#define OUT0_SZ  (N_TOKENS * N_BANKS * BANKSZ)  // 67108864
#define NAT_SZ   4096

#define NBLK          2048
#define WAVES_TOTAL   (NBLK * 4)                 // 8192
#define ROWS_PER_WAVE (N_ROWS / WAVES_TOTAL)     // 64

// One wave per row per iteration; lane L holds elements 2L, 2L+1.
// Persistent waves: each wave loops over 64 rows (stride 8192 rows), with a
// one-row-ahead prefetch. Bank index is invariant along the stride
// (8192 % 32 == 0) so bias is loaded once per wave.
//
// Threshold = 16th-largest monotone key. 10 issue-parallel seed probes at
// 1.25 + n*0.0625 (n=0..9, keys 0xBFA00000 + n*0x80000) bracket the
// |N(0,1)| 16-of-128 order statistic; spacing 0x80000 ulps vs ~0x41000-ulp
// typical 16th/17th order-stat gap makes the exact-count collapse (some
// probe counts exactly 16 -> tail skipped) hit ~45% of rows, and caps the
// dependent binary-search tail at log2(0x80000/gap) ~ 2 probes otherwise.
// Seeding is exact for ANY data (counts are monotone in the probe).
//
// ex-flag: if ANY probe returned count==16, selection k>=T is provably
// tie-free (exactly 16 elements) -> skip the reconstruction ballots.
// With no bit-equal keys the bisection always exits via count==16, so the
// ballot-based tie path only runs for genuine bit-level ties.
__global__ __launch_bounds__(256) void balanced_topk_kernel(
    const float* __restrict__ x,
    const float* __restrict__ bias,
    const float* __restrict__ nat,
    float* __restrict__ out)
{
    const int lane = threadIdx.x & 63;
    const int wid  = (blockIdx.x << 2) | (threadIdx.x >> 6);   // 0..8191

    // second output: pass-through, handled by the first 16 blocks
    if (blockIdx.x < (NAT_SZ / 256)) {
        const int i = blockIdx.x * 256 + threadIdx.x;
        out[(size_t)OUT0_SZ + i] = nat[i];
    }

    // bank of every row this wave touches: (wid + i*8192) & 31 == wid & 31
    const int bank = wid & (N_BANKS - 1);
    const float2 bv = ((const float2*)(bias + (size_t)bank * BANKSZ))[lane];

    const float2* __restrict__ x2 = (const float2*)x;
    float2*       __restrict__ o2 = (float2*)out;

    uint32_t idx = (uint32_t)wid * 64u + (uint32_t)lane;  // float2 index
    const uint32_t stride = (uint32_t)WAVES_TOTAL * 64u;  // 524288 float2/iter

    float2 v = x2[idx];

    for (int i = 0; i < ROWS_PER_WAVE; ++i) {
        const float2  vc  = v;
        const uint32_t cur = idx;
        idx += stride;
        if (i != ROWS_PER_WAVE - 1) v = x2[idx];   // prefetch next row

        const float s0 = fabsf(vc.x) + bv.x;
        const float s1 = fabsf(vc.y) + bv.y;

        // monotone float->uint key (exact for negative scores too)
        const uint32_t u0 = __float_as_uint(s0);
        const uint32_t u1 = __float_as_uint(s1);
        const uint32_t k0 = u0 ^ (uint32_t)(((int32_t)u0 >> 31) | 0x80000000);
        const uint32_t k1 = u1 ^ (uint32_t)(((int32_t)u1 >> 31) | 0x80000000);

#define CNT(Q) (__popcll(__ballot(k0 >= (Q))) + __popcll(__ballot(k1 >= (Q))))

        // 10 independent seed probes: floats 1.25 + n*0.0625, n = 0..9
        // (key = bits | 0x80000000 for positive floats)
        const int c1  = CNT(0xBFA00000u);
        const int c2  = CNT(0xBFA80000u);
        const int c3  = CNT(0xBFB00000u);
        const int c4  = CNT(0xBFB80000u);
        const int c5  = CNT(0xBFC00000u);
        const int c6  = CNT(0xBFC80000u);
        const int c7  = CNT(0xBFD00000u);
        const int c8  = CNT(0xBFD80000u);
        const int c9  = CNT(0xBFE00000u);
        const int c10 = CNT(0xBFE80000u);

        // branchless bracket: LO = largest seed with cnt>=16 (ascending
        // chain, last true wins), HI = smallest seed with cnt<16
        // (descending chain, last true wins)
        uint32_t LO = 0u, HI = 0xFFFFFFFFu;
        if (c1  >= TOPK) LO = 0xBFA00000u;
        if (c2  >= TOPK) LO = 0xBFA80000u;
        if (c3  >= TOPK) LO = 0xBFB00000u;
        if (c4  >= TOPK) LO = 0xBFB80000u;
        if (c5  >= TOPK) LO = 0xBFC00000u;
        if (c6  >= TOPK) LO = 0xBFC80000u;
        if (c7  >= TOPK) LO = 0xBFD00000u;
        if (c8  >= TOPK) LO = 0xBFD80000u;
        if (c9  >= TOPK) LO = 0xBFE00000u;
        if (c10 >= TOPK) LO = 0xBFE80000u;
        if (c10 <  TOPK) HI = 0xBFE80000u;
        if (c9  <  TOPK) HI = 0xBFE00000u;
        if (c8  <  TOPK) HI = 0xBFD80000u;
        if (c7  <  TOPK) HI = 0xBFD00000u;
        if (c6  <  TOPK) HI = 0xBFC80000u;
        if (c5  <  TOPK) HI = 0xBFC00000u;
        if (c4  <  TOPK) HI = 0xBFB80000u;
        if (c3  <  TOPK) HI = 0xBFB00000u;
        if (c2  <  TOPK) HI = 0xBFA80000u;
        if (c1  <  TOPK) HI = 0xBFA00000u;
        // exact-count collapse -> width-1 bracket (tail skipped entirely)
        if (c1  == TOPK) { LO = 0xBFA00000u; HI = 0xBFA00001u; }
        if (c2  == TOPK) { LO = 0xBFA80000u; HI = 0xBFA80001u; }
        if (c3  == TOPK) { LO = 0xBFB00000u; HI = 0xBFB00001u; }
        if (c4  == TOPK) { LO = 0xBFB80000u; HI = 0xBFB80001u; }
        if (c5  == TOPK) { LO = 0xBFC00000u; HI = 0xBFC00001u; }
        if (c6  == TOPK) { LO = 0xBFC80000u; HI = 0xBFC80001u; }
        if (c7  == TOPK) { LO = 0xBFD00000u; HI = 0xBFD00001u; }
        if (c8  == TOPK) { LO = 0xBFD80000u; HI = 0xBFD80001u; }
        if (c9  == TOPK) { LO = 0xBFE00000u; HI = 0xBFE00001u; }
        if (c10 == TOPK) { LO = 0xBFE80000u; HI = 0xBFE80001u; }

        bool ex = (c1 == TOPK) | (c2 == TOPK) | (c3 == TOPK) | (c4 == TOPK) |
                  (c5 == TOPK) | (c6 == TOPK) | (c7 == TOPK) | (c8 == TOPK) |
                  (c9 == TOPK) | (c10 == TOPK);

        // dependent tail: invariant cnt(LO) >= 16 > cnt(HI)
        while (HI - LO > 1u) {
            const uint32_t Q = LO + ((HI - LO) >> 1);
            const int c = CNT(Q);
            const uint32_t nHI = (c >= TOPK) ? HI : Q;
            LO = (c >= TOPK) ? Q : LO;
            HI = (c == TOPK) ? (Q + 1u) : nHI;
            ex = ex || (c == TOPK);
        }
        const uint32_t T = LO;   // the 16th-largest key
#undef CNT

        float2 o;
        if (ex) {
            // some probe counted exactly 16 -> {k >= T} has exactly 16
            // elements, no straddling ties: no reconstruction ballots needed
            o.x = (k0 >= T) ? vc.x : 0.0f;
            o.y = (k1 >= T) ? vc.y : 0.0f;
        } else {
            // bit-level ties straddle the threshold (rare): fill remaining
            // r slots in element-index order
            const unsigned long long g0 = __ballot(k0 >= T);
            const unsigned long long g1 = __ballot(k1 >= T);
            const int cge = __popcll(g0) + __popcll(g1);
            if (cge == TOPK) {
                o.x = (k0 >= T) ? vc.x : 0.0f;
                o.y = (k1 >= T) ? vc.y : 0.0f;
            } else {
                const unsigned long long e0 = __ballot(k0 == T);
                const unsigned long long e1 = __ballot(k1 == T);
                const int r = TOPK - (cge - (__popcll(e0) + __popcll(e1)));
                const unsigned long long lt = (1ull << lane) - 1ull;
                const int rank0 = __popcll(e0 & lt) + __popcll(e1 & lt);
                const int rank1 = rank0 + ((k0 == T) ? 1 : 0);
                const bool s0sel = (k0 > T) || ((k0 == T) && (rank0 < r));
                const bool s1sel = (k1 > T) || ((k1 == T) && (rank1 < r));
                o.x = s0sel ? vc.x : 0.0f;
                o.y = s1sel ? vc.y : 0.0f;
            }
        }
        o2[cur] = o;
    }
}

extern "C" void kernel_launch(void* const* d_in, const int* in_sizes, int n_in,
                              void* d_out, int out_size, void* d_ws, size_t ws_size,
                              hipStream_t stream) {
    const float* x    = (const float*)d_in[0];
    const float* bias = (const float*)d_in[1];
    const float* nat  = (const float*)d_in[2];
    float* out = (float*)d_out;

    balanced_topk_kernel<<<dim3(NBLK), dim3(256), 0, stream>>>(x, bias, nat, out);
}

// Round 4
// 445.817 us; speedup vs baseline: 1.1545x; 1.0927x over previous
//
#include <hip/hip_runtime.h>
#include <cstdint>

// x: [4,4096,4096] fp32 -> rows of 128 over [T=16384, N_BANKS=32, BANK=128]
// scores = |x| + bias[bank][:]; mask = top-16 per row (ties -> lowest index);
// out0 = x * mask; out1 = num_assigned_tokens (pass-through).
//
// Round-3 finding: the kernel is SALU-bound (VGPR_Count=8 -- compiler
// scalarized all ballot-count/bracket logic; SALU is ONE pipe per CU shared
// by 4 SIMDs; ~140 SALU/row x 2048 rows/CU ~= 120us). Fix: pin ballot masks
// into VGPRs via empty inline asm so __popcll lowers to v_bcnt_u32_b32
// (VALU, 4 SIMDs/CU) and bracket math stays vector. Do NOT reintroduce the
// float4 2-row layout (rounds 1-2: 195-199us).
#define BANKSZ   128
#define N_BANKS  32
#define TOPK     16
#define N_TOKENS (4 * 4096)
#define N_ROWS   (N_TOKENS * N_BANKS)           // 524288
#define OUT0_SZ  (N_TOKENS * N_BANKS * BANKSZ)  // 67108864
#define NAT_SZ   4096

#define NBLK          2048
#define WAVES_TOTAL   (NBLK * 4)                 // 8192
#define ROWS_PER_WAVE (N_ROWS / WAVES_TOTAL)     // 64

// Force a wave-uniform 64-bit value into VGPRs and make it opaque to
// uniformity analysis: downstream __popcll becomes v_bcnt_u32_b32 (VALU)
// instead of s_bcnt1_b64 (SALU), and dependent arithmetic stays VALU.
__device__ __forceinline__ unsigned long long vgpr_pin(unsigned long long m) {
    asm("" : "+v"(m));
    return m;
}

// One wave per row per iteration; lane L holds elements 2L, 2L+1.
// Persistent waves: 64 rows per wave (stride 8192 rows), one-row-ahead
// prefetch. Bank index invariant along the stride, bias loaded once.
//
// Threshold = 16th-largest monotone key. 6 issue-parallel VALU-counted seed
// probes at uniformly spaced keys S_i = 0xBF880000 + i*0x140000 (floats
// 1.21875 .. 2.0, step 0.15625) bracket the |N(0,1)| 16-of-128 order
// statistic (mean ~1.53, sd ~0.12 -> ~99.5% of rows land inside). Bracket
// selection is pure arithmetic: j = #(c_i >= 16) (counts are monotone
// decreasing in i), LO = S_j (or 0 if j==0), HI = S_{j+1} (or ~0u if j==6).
// Short dependent scalar tail bisects [LO,HI) with exact-count collapse
// (c==16 -> done); exact for ANY data, only speed is distribution-tuned.
__global__ __launch_bounds__(256) void balanced_topk_kernel(
    const float* __restrict__ x,
    const float* __restrict__ bias,
    const float* __restrict__ nat,
    float* __restrict__ out)
{
    const int lane = threadIdx.x & 63;
    const int wid  = (blockIdx.x << 2) | (threadIdx.x >> 6);   // 0..8191

    // second output: pass-through, handled by the first 16 blocks
    if (blockIdx.x < (NAT_SZ / 256)) {
        const int i = blockIdx.x * 256 + threadIdx.x;
        out[(size_t)OUT0_SZ + i] = nat[i];
    }

    // bank of every row this wave touches: (wid + i*8192) & 31 == wid & 31
    const int bank = wid & (N_BANKS - 1);
    const float2 bv = ((const float2*)(bias + (size_t)bank * BANKSZ))[lane];

    const float2* __restrict__ x2 = (const float2*)x;
    float2*       __restrict__ o2 = (float2*)out;

    uint32_t idx = (uint32_t)wid * 64u + (uint32_t)lane;  // float2 index
    const uint32_t stride = (uint32_t)WAVES_TOTAL * 64u;  // 524288 float2/iter

    float2 v = x2[idx];

    for (int i = 0; i < ROWS_PER_WAVE; ++i) {
        const float2  vc  = v;
        const uint32_t cur = idx;
        idx += stride;
        if (i != ROWS_PER_WAVE - 1) v = x2[idx];   // prefetch next row

        const float s0 = fabsf(vc.x) + bv.x;
        const float s1 = fabsf(vc.y) + bv.y;

        // monotone float->uint key (exact for negative scores too)
        const uint32_t u0 = __float_as_uint(s0);
        const uint32_t u1 = __float_as_uint(s1);
        const uint32_t k0 = u0 ^ (uint32_t)(((int32_t)u0 >> 31) | 0x80000000);
        const uint32_t k1 = u1 ^ (uint32_t)(((int32_t)u1 >> 31) | 0x80000000);

        // VALU-counted probe: v_cmp ballots + v_bcnt popcounts (no SALU)
#define VCNT(Q) ((uint32_t)(__popcll(vgpr_pin(__ballot(k0 >= (Q)))) \
                          + __popcll(vgpr_pin(__ballot(k1 >= (Q))))))

        // 6 seed probes, uniformly spaced keys S_i = 0xBF880000 + i*0x140000
        const uint32_t c1 = VCNT(0xBF9C0000u);   // 1.21875
        const uint32_t c2 = VCNT(0xBFB00000u);   // 1.375
        const uint32_t c3 = VCNT(0xBFC40000u);   // 1.53125
        const uint32_t c4 = VCNT(0xBFD80000u);   // 1.6875
        const uint32_t c5 = VCNT(0xBFEC0000u);   // 1.84375
        const uint32_t c6 = VCNT(0xC0000000u);   // 2.0
#undef VCNT

        // j = #(c_i >= 16): arithmetic flags, no compare/cselect chains.
        // c in [0,128]: (c+112)>>7 is 1 iff c>=16 (c+112 <= 240 < 256).
        const uint32_t j = ((c1 + 112u) >> 7) + ((c2 + 112u) >> 7)
                         + ((c3 + 112u) >> 7) + ((c4 + 112u) >> 7)
                         + ((c5 + 112u) >> 7) + ((c6 + 112u) >> 7);

        // LO = S_j (counts monotone decreasing -> invariant cnt(LO) >= 16),
        // HI = S_{j+1} (cnt(HI) < 16). j*0x140000 = (j<<20)+(j<<18).
        const uint32_t off = (j << 20) + (j << 18);
        uint32_t LOv = 0xBF880000u + off;
        LOv = (j == 0u) ? 0u : LOv;               // j==0: cnt(0)=128>=16 ok
        uint32_t HIv = 0xBF9C0000u + off;         // = LO + 0x140000
        HIv = (j == 6u) ? 0xFFFFFFFFu : HIv;      // j==6: cnt(~0)=0 < 16 ok

        uint32_t LO = (uint32_t)__builtin_amdgcn_readfirstlane(LOv);
        uint32_t HI = (uint32_t)__builtin_amdgcn_readfirstlane(HIv);

        // dependent scalar tail (~2 iters avg): invariant cnt(LO)>=16>cnt(HI)
#define CNT(Q) (__popcll(__ballot(k0 >= (Q))) + __popcll(__ballot(k1 >= (Q))))
        while (HI - LO > 1u) {
            const uint32_t Q = LO + ((HI - LO) >> 1);
            const int c = CNT(Q);
            const uint32_t nHI = (c >= TOPK) ? HI : Q;
            LO = (c >= TOPK) ? Q : LO;
            HI = (c == TOPK) ? (Q + 1u) : nHI;    // exact-count collapse
        }
        const uint32_t T = LO;   // separating threshold for the top 16
#undef CNT

        // reconstruction
        const unsigned long long g0 = __ballot(k0 >= T);
        const unsigned long long g1 = __ballot(k1 >= T);
        const int cge = __popcll(g0) + __popcll(g1);

        float2 o;
        if (cge == TOPK) {
            // no ties straddling the threshold (overwhelmingly common)
            o.x = (k0 >= T) ? vc.x : 0.0f;
            o.y = (k1 >= T) ? vc.y : 0.0f;
        } else {
            // ties at T: fill remaining r slots in element-index order
            const unsigned long long e0 = __ballot(k0 == T);
            const unsigned long long e1 = __ballot(k1 == T);
            const int r = TOPK - (cge - (__popcll(e0) + __popcll(e1)));
            const unsigned long long lt = (1ull << lane) - 1ull;
            const int rank0 = __popcll(e0 & lt) + __popcll(e1 & lt);
            const int rank1 = rank0 + ((k0 == T) ? 1 : 0);
            const bool sel0 = (k0 > T) || ((k0 == T) && (rank0 < r));
            const bool sel1 = (k1 > T) || ((k1 == T) && (rank1 < r));
            o.x = sel0 ? vc.x : 0.0f;
            o.y = sel1 ? vc.y : 0.0f;
        }
        o2[cur] = o;
    }
}

extern "C" void kernel_launch(void* const* d_in, const int* in_sizes, int n_in,
                              void* d_out, int out_size, void* d_ws, size_t ws_size,
                              hipStream_t stream) {
    const float* x    = (const float*)d_in[0];
    const float* bias = (const float*)d_in[1];
    const float* nat  = (const float*)d_in[2];
    float* out = (float*)d_out;

    balanced_topk_kernel<<<dim3(NBLK), dim3(256), 0, stream>>>(x, bias, nat, out);
}